// Round 9
// baseline (160.439 us; speedup 1.0000x reference)
//
#include <hip/hip_runtime.h>
#include <math.h>

#define HALO 4
#define TWX 72
#define QIW 528
#define QIH 520

typedef float f4 __attribute__((ext_vector_type(4)));

#if __has_builtin(__builtin_amdgcn_fractf)
#define FRACTF(x) __builtin_amdgcn_fractf(x)
#else
#define FRACTF(x) ((x) - floorf(x))
#endif
#if __has_builtin(__builtin_amdgcn_exp2f)
#define EXP2F(x) __builtin_amdgcn_exp2f(x)
#else
#define EXP2F(x) exp2f(x)
#endif
#if __has_builtin(__builtin_amdgcn_logf)
#define LOG2F(x) __builtin_amdgcn_logf(x)
#else
#define LOG2F(x) log2f(x)
#endif

// tbl layout (floats):
// [0..23] cos_q  [24..47] sin_q  [48..71] cos_q*SC  [72..95] sin_q*SC
// [96..103] wn_norm*log2e  [104] irt*log2e  [105] gamma  [106] gain
// [172] fastconv ok flag (int)  [180..183] per-bank equal weight
__global__ __launch_bounds__(64) void gp_setup(const float* __restrict__ gain,
                                               const float* __restrict__ lrt,
                                               const float* __restrict__ rlg,
                                               const float* __restrict__ Wb,
                                               float* __restrict__ tbl) {
  int t = threadIdx.x;
  __shared__ float wtmp[8];
  if (t < 8) {
    float tn = (float)(t + 1) * 0.375f;
    wtmp[t] = expf(-0.5f * tn * tn);
  }
  if (t < 24) {
    float th = (6.283185307179586f * (float)t) / 24.0f;
    float c = cosf(th), s = sinf(th);
    const float sc = (float)(512.0 / 511.0);
    tbl[t] = c; tbl[24 + t] = s; tbl[48 + t] = c * sc; tbl[72 + t] = s * sc;
  }
  __syncthreads();
  if (t == 0) {
    const float L2E = 1.44269504088896340736f;
    float sum = 0.f;
    for (int n = 0; n < 8; ++n) sum += wtmp[n];
    for (int n = 0; n < 8; ++n) tbl[96 + n] = (wtmp[n] / sum) * L2E;
    float rt = expf(lrt[0]);
    rt = fminf(fmaxf(rt, 0.001f), 2.0f);
    float sg = 1.0f / (1.0f + expf(-rlg[0]));
    float rho = sg * 0.95f + 0.05f;
    tbl[104] = (1.0f / rt) * L2E;
    tbl[105] = 1.0f / (rho + 1e-8f);
    tbl[106] = fmaxf(gain[0], 0.001f);

    const int K0[7] = {14,15,23,24,25,33,34};
    const int K1[7] = {2,9,17,24,31,39,46};
    const int K2[7] = {4,11,17,24,31,37,44};
    const int K3[7] = {19,20,23,24,25,28,29};
    const int* KK[4] = {K0,K1,K2,K3};
    int ok = 1;
    for (int o = 0; o < 4; ++o) {
      float w0v = Wb[o * 49 + KK[o][0]];
      if (w0v == 0.f) ok = 0;
      unsigned long long mask = 0;
      for (int t2 = 0; t2 < 7; ++t2) mask |= 1ull << KK[o][t2];
      for (int k = 0; k < 49; ++k) {
        float w = Wb[o * 49 + k];
        int nz = (w != 0.f);
        int want = (int)((mask >> k) & 1ull);
        if (nz != want) ok = 0;
        if (nz && w != w0v) ok = 0;
      }
      tbl[180 + o] = w0v;
    }
    ((int*)tbl)[172] = ok;
  }
}

__device__ inline float fmv(const float* __restrict__ x0p, const float* __restrict__ x1p,
                            int Y, int X) {
  int cY = min(max(Y, 0), 511);
  int cX = min(max(X, 0), 511);
  size_t o = (size_t)cY * 512 + cX;
  float a = x0p[o], b = x1p[o];
  float f = sqrtf(a * a + b * b);
  return ((unsigned)X < 512u && (unsigned)Y < 512u) ? f : 0.f;
}

// Fast prepass: 4 pre-differenced quads per thread, vectorized interior loads.
__global__ __launch_bounds__(256) void gp_quadF(const float* __restrict__ x,
                                                f4* __restrict__ qimg) {
  int g = blockIdx.x * 256 + threadIdx.x;
  if (g >= QIH * 132) return;
  int b = blockIdx.y;
  int y = g / 132, xg = g - y * 132;
  int X = xg * 4 - 4, Y = y - 4;
  const float* __restrict__ x0p = x + (size_t)b * 2 * 512 * 512;
  const float* __restrict__ x1p = x0p + 512 * 512;

  float F0[5], F1[5];
  if (X >= 0 && X <= 507 && Y >= 0 && Y <= 510) {
    size_t r0 = (size_t)Y * 512 + X, r1 = r0 + 512;
    f4 a0 = *(const f4*)(x0p + r0); float a4 = x0p[r0 + 4];
    f4 b0 = *(const f4*)(x1p + r0); float b4 = x1p[r0 + 4];
    f4 c0 = *(const f4*)(x0p + r1); float c4 = x0p[r1 + 4];
    f4 d0 = *(const f4*)(x1p + r1); float d4 = x1p[r1 + 4];
    #pragma unroll
    for (int i = 0; i < 4; ++i) {
      F0[i] = sqrtf(a0[i] * a0[i] + b0[i] * b0[i]);
      F1[i] = sqrtf(c0[i] * c0[i] + d0[i] * d0[i]);
    }
    F0[4] = sqrtf(a4 * a4 + b4 * b4);
    F1[4] = sqrtf(c4 * c4 + d4 * d4);
  } else {
    #pragma unroll
    for (int i = 0; i < 5; ++i) {
      F0[i] = fmv(x0p, x1p, Y, X + i);
      F1[i] = fmv(x0p, x1p, Y + 1, X + i);
    }
  }
  f4* dst = qimg + (size_t)(b * QIH + y) * QIW + xg * 4;
  #pragma unroll
  for (int k = 0; k < 4; ++k) {
    float d0 = F0[k + 1] - F0[k];
    f4 q;
    q[0] = F0[k];
    q[1] = d0;
    q[2] = F1[k] - F0[k];
    q[3] = (F1[k + 1] - F1[k]) - d0;
    dst[k] = q;
  }
}

__device__ inline float finish(float SY, float CX, float a0, float a1, float a2,
                               float a3, const float* __restrict__ cen,
                               float irt2, float gamma, float gainc) {
  const float TP  = 6.283185307179586f;
  const float PIF = 3.14159265358979323846f;
  const float HP  = 1.57079632679489661923f;
  float hat = atan2f(SY, CX);
  float r1 = hat + TP;
  r1 = (r1 >= TP) ? (r1 - TP) : r1;
  float theta = (r1 >= PIF) ? (r1 - PIF) : r1;
  float dist[4];
  #pragma unroll
  for (int o = 0; o < 4; ++o) {
    float d = theta - cen[o] + HP;
    d -= (d >= PIF) ? PIF : 0.f;
    d += (d < 0.f) ? PIF : 0.f;
    dist[o] = fabsf(d - HP);
  }
  float mn = fminf(fminf(dist[0], dist[1]), fminf(dist[2], dist[3]));
  float m2 = mn * irt2;
  float eo[4], Z = 0.f;
  #pragma unroll
  for (int o = 0; o < 4; ++o) { eo[o] = EXP2F(fmaf(-irt2, dist[o], m2)); Z += eo[o]; }
  float invZ = 1.0f / Z;
  float sh[4], Zs = 0.f;
  #pragma unroll
  for (int o = 0; o < 4; ++o) {
    sh[o] = EXP2F(gamma * LOG2F(fmaf(eo[o], invZ, 1e-12f)));
    Zs += sh[o];
  }
  float wsi = 1.0f / (Zs + 1e-8f);
  return gainc * ((a0 * sh[0] + a1 * sh[1] + a2 * sh[2] + a3 * sh[3]) * wsi);
}

#define TN0 0.375f
#define TN1 0.75f
#define TN2 1.125f
#define TN3 1.5f
#define TN4 1.875f
#define TN5 2.25f
#define TN6 2.625f
#define TN7 3.0f

// x-side: shared across the thread's 4 rows (coords > 0 so trunc == floor)
#define XS(n) \
  float px##n = fmaf(-cs, TN##n, axl); \
  int   ix##n = (int)px##n; \
  float fx##n = FRACTF(px##n);

// VMEM sample issue for radius n, row k
#define BISS(n,k) \
  float pyB##n##k = fmaf(-sn, TN##n, ayl##k); \
  int   iyB##n##k = (int)pyB##n##k; \
  float fyB##n##k = FRACTF(pyB##n##k); \
  f4    B##n##k   = qg[iyB##n##k * QIW + ix##n];

// LDS sample for radius n, row k
#define ASMP(n,k) \
  float pa##n##k = fmaf(-sn, TN##n, ayl##k); \
  int   ia##n##k = (int)pa##n##k; \
  float fa##n##k = FRACTF(pa##n##k); \
  f4    A##n##k  = Qd[ia##n##k * 72 + ix##n];

#define ABL(n,k) fmaf(fa##n##k, fmaf(fx##n, A##n##k[3], A##n##k[2]), fmaf(fx##n, A##n##k[1], A##n##k[0]))
#define BBL(n,k) fmaf(fyB##n##k, fmaf(fx##n, B##n##k[3], B##n##k[2]), fmaf(fx##n, B##n##k[1], B##n##k[0]))

#define AROW(k) \
  ASMP(0,k) ASMP(1,k) ASMP(2,k) ASMP(3,k) ASMP(4,k) \
  float e2##k = wn0 * ABL(0,k); \
  e2##k = fmaf(wn1, ABL(1,k), e2##k); \
  e2##k = fmaf(wn2, ABL(2,k), e2##k); \
  e2##k = fmaf(wn3, ABL(3,k), e2##k); \
  e2##k = fmaf(wn4, ABL(4,k), e2##k);

#define BCONS(k) \
  e2##k = fmaf(wn5, BBL(5,k), e2##k); \
  e2##k = fmaf(wn6, BBL(6,k), e2##k); \
  e2##k = fmaf(wn7, BBL(7,k), e2##k); \
  { float e = EXP2F(e2##k); SY##k = fmaf(e, snq, SY##k); CX##k = fmaf(e, csq, CX##k); }

// Main: 64x16 tile, 256 threads, 4 pixels/thread (rows ty, ty+4, ty+8, ty+12),
// shared x-side coordinate chain. Radii 0..4 from LDS, 5..7 from the global
// quad image (own-XCD L2). Per q: 12 VMEM quads issued first (fenced live by
// asm), 20 LDS samples processed during their flight, then B consumed in
// strict n-order per row -> per-pixel fma chain identical to R8.
__global__ __launch_bounds__(256, 4) void gp_main9(const f4* __restrict__ qimg,
                                                   const float* __restrict__ x,
                                                   const float* __restrict__ Wb,
                                                   const float* __restrict__ cen,
                                                   const float* __restrict__ tbl,
                                                   float* __restrict__ out) {
  __shared__ f4    Qd[24 * 72];   // 27.6 KB
  __shared__ float Sm[22 * 70];   // 6.2 KB

  const int tx = threadIdx.x;     // 0..63 (wave = one pixel row per step)
  const int ty = threadIdx.y;     // 0..3
  const int tid = ty * 64 + tx;
  int wg = blockIdx.x;            // 2048 = 8 xcd-chunks of 256
  int swz = (wg & 7) * 256 + (wg >> 3);
  int bx = swz & 7;
  int by = (swz >> 3) & 31;
  int b  = swz >> 8;

  const float* __restrict__ x0p = x + (size_t)b * 2 * 512 * 512;
  const float* __restrict__ x1p = x0p + 512 * 512;
  // window (r,c), r in [0,24): image row by*16-4+r, col bx*64-4+c
  const f4* __restrict__ qg = qimg + (size_t)(b * QIH + by * 16) * QIW + bx * 64;

  // Stage LDS quad window (copy of qimg window) and Sm = x0+x1 (halo 3).
  #pragma unroll
  for (int it = 0; it < 7; ++it) {
    int idx = tid + it * 256;
    if (idx < 24 * 72) {
      int r = idx / 72, c = idx - r * 72;
      Qd[idx] = qg[r * QIW + c];
    }
  }
  const int sy0 = by * 16 - 3, sx0 = bx * 64 - 3;
  #pragma unroll
  for (int it = 0; it < 7; ++it) {
    int idx = tid + it * 256;
    if (idx < 22 * 70) {
      int r = idx / 70, c = idx - r * 70;
      int gy = sy0 + r, gx = sx0 + c;
      float a = 0.f, bv = 0.f;
      if ((unsigned)gx < 512u && (unsigned)gy < 512u) {
        size_t o = (size_t)gy * 512 + gx;
        a = x0p[o]; bv = x1p[o];
      }
      Sm[idx] = a + bv;
    }
  }
  __syncthreads();

  const int gi = bx * 64 + tx;
  const int gj0 = by * 16 + ty;    // rows gj0 + 4k, k=0..3
  const float SC = (float)(512.0 / 511.0);
  const float bx0f = (float)(bx * 64 - 4);
  const float by0f = (float)(by * 16 - 4);
  const float axl  = fmaf((float)gi, SC, -0.5f) - bx0f;
  const float ayl0 = fmaf((float)gj0,        SC, -0.5f) - by0f;
  const float ayl1 = fmaf((float)(gj0 + 4),  SC, -0.5f) - by0f;
  const float ayl2 = fmaf((float)(gj0 + 8),  SC, -0.5f) - by0f;
  const float ayl3 = fmaf((float)(gj0 + 12), SC, -0.5f) - by0f;

  const float wn0 = tbl[96], wn1 = tbl[97], wn2 = tbl[98], wn3 = tbl[99];
  const float wn4 = tbl[100], wn5 = tbl[101], wn6 = tbl[102], wn7 = tbl[103];

  float SY0 = 0.f, CX0 = 0.f, SY1 = 0.f, CX1 = 0.f;
  float SY2 = 0.f, CX2 = 0.f, SY3 = 0.f, CX3 = 0.f;

  for (int q = 0; q < 24; ++q) {
    const float cs = tbl[48 + q];
    const float sn = tbl[72 + q];
    const float csq = tbl[q];
    const float snq = tbl[24 + q];
    // shared x-side for all 4 rows
    XS(0) XS(1) XS(2) XS(3) XS(4) XS(5) XS(6) XS(7)
    // issue 12 VMEM gathers (radii 5..7 x 4 rows)
    BISS(5,0) BISS(5,1) BISS(5,2) BISS(5,3)
    BISS(6,0) BISS(6,1) BISS(6,2) BISS(6,3)
    BISS(7,0) BISS(7,1) BISS(7,2) BISS(7,3)
    // LDS radii 0..4 for all 4 rows while VMEM flies
    AROW(0) AROW(1) AROW(2) AROW(3)
    // fence the VMEM batch live, then consume in n-order per row
    asm volatile("" : : "v"(B50), "v"(B51), "v"(B52), "v"(B53),
                        "v"(B60), "v"(B61), "v"(B62), "v"(B63),
                        "v"(B70), "v"(B71), "v"(B72), "v"(B73));
    BCONS(0) BCONS(1) BCONS(2) BCONS(3)
  }

  // Conv (Sm stride 70, halo 3): verified line-mask fast path, dense fallback.
  const int* ti = (const int*)tbl;
  float a0k[4], a1k[4], a2k[4], a3k[4];
  if (ti[172]) {
    #pragma unroll
    for (int k = 0; k < 4; ++k) {
      int cc = (ty + 4 * k + 3) * 70 + tx + 3;
      float sC = Sm[cc];
      float H3 = (Sm[cc - 1] + sC) + Sm[cc + 1];
      float V3 = (Sm[cc - 70] + sC) + Sm[cc + 70];
      a0k[k] = tbl[180] * (H3 + ((Sm[cc - 73] + Sm[cc - 72]) + (Sm[cc + 72] + Sm[cc + 73])));
      a1k[k] = tbl[181] * (V3 + ((Sm[cc - 211] + Sm[cc - 141]) + (Sm[cc + 141] + Sm[cc + 211])));
      a2k[k] = tbl[182] * (V3 + ((Sm[cc - 209] + Sm[cc - 139]) + (Sm[cc + 139] + Sm[cc + 209])));
      a3k[k] = tbl[183] * (H3 + ((Sm[cc - 68] + Sm[cc - 67]) + (Sm[cc + 67] + Sm[cc + 68])));
    }
  } else {
    #pragma unroll
    for (int k = 0; k < 4; ++k) { a0k[k] = a1k[k] = a2k[k] = a3k[k] = 0.f; }
    for (int kj = 0; kj < 7; ++kj)
      for (int ki = 0; ki < 7; ++ki) {
        int kk = kj * 7 + ki;
        float w0 = Wb[kk], w1 = Wb[49 + kk], w2 = Wb[98 + kk], w3 = Wb[147 + kk];
        #pragma unroll
        for (int k = 0; k < 4; ++k) {
          float s = Sm[(ty + 4 * k + kj) * 70 + (tx + ki)];
          a0k[k] = fmaf(s, w0, a0k[k]); a1k[k] = fmaf(s, w1, a1k[k]);
          a2k[k] = fmaf(s, w2, a2k[k]); a3k[k] = fmaf(s, w3, a3k[k]);
        }
      }
  }

  const float irt2  = tbl[104];
  const float gamma = tbl[105];
  const float gainc = tbl[106];

  float o0 = finish(SY0, CX0, a0k[0], a1k[0], a2k[0], a3k[0], cen, irt2, gamma, gainc);
  float o1 = finish(SY1, CX1, a0k[1], a1k[1], a2k[1], a3k[1], cen, irt2, gamma, gainc);
  float o2 = finish(SY2, CX2, a0k[2], a1k[2], a2k[2], a3k[2], cen, irt2, gamma, gainc);
  float o3 = finish(SY3, CX3, a0k[3], a1k[3], a2k[3], a3k[3], cen, irt2, gamma, gainc);

  size_t ob = ((size_t)b * 512 + gj0) * 512 + gi;
  out[ob] = o0;
  out[ob + 4 * 512] = o1;
  out[ob + 8 * 512] = o2;
  out[ob + 12 * 512] = o3;
}

// Fallback (ws too small): all-LDS single-kernel (R2-equivalent, proven).
__global__ __launch_bounds__(256) void gp_main_fb(const float* __restrict__ x,
                                                  const float* __restrict__ Wb,
                                                  const float* __restrict__ cen,
                                                  const float* __restrict__ tbl,
                                                  float* __restrict__ out) {
  __shared__ float Fm[12 * TWX];
  __shared__ float Sm[12 * TWX];
  __shared__ f4    Qd[12 * TWX];
  const int tx = threadIdx.x;
  const int ty = threadIdx.y;
  const int tid = ty * 64 + tx;
  const int bx0 = blockIdx.x * 64 - HALO;
  const int by0 = blockIdx.y * 4 - HALO;
  const int b = blockIdx.z;
  const float* __restrict__ x0p = x + (size_t)b * 2 * 512 * 512;
  const float* __restrict__ x1p = x0p + 512 * 512;
  #pragma unroll
  for (int it = 0; it < 4; ++it) {
    int idx = tid + it * 256;
    if (idx < 864) {
      int r = idx / TWX, c = idx - r * TWX;
      int gy = by0 + r, gx = bx0 + c;
      float a = 0.f, bv = 0.f;
      if ((unsigned)gx < 512u && (unsigned)gy < 512u) {
        size_t o = (size_t)gy * 512 + gx;
        a = x0p[o]; bv = x1p[o];
      }
      Fm[idx] = sqrtf(a * a + bv * bv);
      Sm[idx] = a + bv;
    }
  }
  __syncthreads();
  #pragma unroll
  for (int it = 0; it < 4; ++it) {
    int idx = tid + it * 256;
    if (idx < 864) {
      int r = idx / TWX, c = idx - r * TWX;
      int r1 = (r < 11) ? r + 1 : r;
      int c1 = (c < TWX - 1) ? c + 1 : c;
      float v00 = Fm[r * TWX + c],  v01 = Fm[r * TWX + c1];
      float v10 = Fm[r1 * TWX + c], v11 = Fm[r1 * TWX + c1];
      f4 qv; qv[0] = v00; qv[1] = v01 - v00; qv[2] = v10 - v00;
      qv[3] = (v11 - v10) - (v01 - v00);
      Qd[idx] = qv;
    }
  }
  __syncthreads();
  const int gi = bx0 + HALO + tx;
  const int gj = by0 + HALO + ty;
  const float SC = (float)(512.0 / 511.0);
  const float axl = fmaf((float)gi, SC, -0.5f) - (float)bx0;
  const float ayl = fmaf((float)gj, SC, -0.5f) - (float)by0;
  float wn[8];
  #pragma unroll
  for (int n = 0; n < 8; ++n) wn[n] = tbl[96 + n];
  float SY = 0.f, CX = 0.f;
  for (int q = 0; q < 24; ++q) {
    const float csx = tbl[48 + q];
    const float ssy = tbl[72 + q];
    float e2 = 0.f;
    #pragma unroll
    for (int n = 0; n < 8; ++n) {
      const float tn = 0.375f * (float)(n + 1);
      float px = fmaf(-csx, tn, axl);
      float py = fmaf(-ssy, tn, ayl);
      int ix = (int)px, iy = (int)py;
      float fx = FRACTF(px), fy = FRACTF(py);
      f4 v = Qd[iy * TWX + ix];
      float s = fmaf(fy, fmaf(fx, v[3], v[2]), fmaf(fx, v[1], v[0]));
      e2 = fmaf(wn[n], s, e2);
    }
    float e = EXP2F(e2);
    SY = fmaf(e, tbl[24 + q], SY);
    CX = fmaf(e, tbl[q], CX);
  }
  const int* ti = (const int*)tbl;
  const int ccen = (ty + 4) * TWX + tx + 4;
  float a0, a1, a2, a3;
  if (ti[172]) {
    float sCt = Sm[ccen];
    float H3 = (Sm[ccen - 1] + sCt) + Sm[ccen + 1];
    float V3 = (Sm[ccen - TWX] + sCt) + Sm[ccen + TWX];
    a0 = tbl[180] * (H3 + ((Sm[ccen - 75] + Sm[ccen - 74]) + (Sm[ccen + 74] + Sm[ccen + 75])));
    a1 = tbl[181] * (V3 + ((Sm[ccen - 217] + Sm[ccen - 145]) + (Sm[ccen + 145] + Sm[ccen + 217])));
    a2 = tbl[182] * (V3 + ((Sm[ccen - 215] + Sm[ccen - 143]) + (Sm[ccen + 143] + Sm[ccen + 215])));
    a3 = tbl[183] * (H3 + ((Sm[ccen - 70] + Sm[ccen - 69]) + (Sm[ccen + 69] + Sm[ccen + 70])));
  } else {
    a0 = a1 = a2 = a3 = 0.f;
    for (int kj = 0; kj < 7; ++kj)
      for (int ki = 0; ki < 7; ++ki) {
        float s = Sm[(ty + 1 + kj) * TWX + (tx + 1 + ki)];
        int k = kj * 7 + ki;
        a0 = fmaf(s, Wb[k], a0); a1 = fmaf(s, Wb[49 + k], a1);
        a2 = fmaf(s, Wb[98 + k], a2); a3 = fmaf(s, Wb[147 + k], a3);
      }
  }
  const float irt2  = tbl[104];
  const float gamma = tbl[105];
  const float gainc = tbl[106];
  float ov = finish(SY, CX, a0, a1, a2, a3, cen, irt2, gamma, gainc);
  out[((size_t)b * 512 + gj) * 512 + gi] = ov;
}

extern "C" void kernel_launch(void* const* d_in, const int* in_sizes, int n_in,
                              void* d_out, int out_size, void* d_ws, size_t ws_size,
                              hipStream_t stream) {
  const float* x    = (const float*)d_in[0];
  const float* gain = (const float*)d_in[1];
  const float* lrt  = (const float*)d_in[2];
  const float* rlg  = (const float*)d_in[3];
  const float* Wb   = (const float*)d_in[4];
  const float* cen  = (const float*)d_in[5];
  float* tbl = (float*)d_ws;

  gp_setup<<<1, 64, 0, stream>>>(gain, lrt, rlg, Wb, tbl);

  size_t need = 4096 + (size_t)8 * QIH * QIW * sizeof(f4);
  if (ws_size >= need) {
    f4* qimg = (f4*)((char*)d_ws + 4096);
    gp_quadF<<<dim3((QIH * 132 + 255) / 256, 8), 256, 0, stream>>>(x, qimg);
    gp_main9<<<dim3(2048), dim3(64, 4), 0, stream>>>(qimg, x, Wb, cen, tbl, (float*)d_out);
  } else {
    gp_main_fb<<<dim3(8, 128, 8), dim3(64, 4), 0, stream>>>(x, Wb, cen, tbl, (float*)d_out);
  }
}

// Round 10
// 136.264 us; speedup vs baseline: 1.1774x; 1.1774x over previous
//
#include <hip/hip_runtime.h>
#include <math.h>

#define HALO 4
#define TWX 72
#define TWY 12
#define NST (TWX*TWY)   // 864

#if __has_builtin(__builtin_amdgcn_fractf)
#define FRACTF(x) __builtin_amdgcn_fractf(x)
#else
#define FRACTF(x) ((x) - floorf(x))
#endif
#if __has_builtin(__builtin_amdgcn_exp2f)
#define EXP2F(x) __builtin_amdgcn_exp2f(x)
#else
#define EXP2F(x) exp2f(x)
#endif
#if __has_builtin(__builtin_amdgcn_logf)
#define LOG2F(x) __builtin_amdgcn_logf(x)
#else
#define LOG2F(x) log2f(x)
#endif

// tbl layout (floats):
// [0..23] cos_q  [24..47] sin_q  [48..71] cos_q*SC  [72..95] sin_q*SC
// [96..103] wn_norm*log2e  [104] irt*log2e  [105] gamma  [106] gain
// [172] fastconv ok flag (int)  [180..183] per-bank equal weight
__global__ __launch_bounds__(64) void gp_setup(const float* __restrict__ gain,
                                               const float* __restrict__ lrt,
                                               const float* __restrict__ rlg,
                                               const float* __restrict__ Wb,
                                               float* __restrict__ tbl) {
  int t = threadIdx.x;
  __shared__ float wtmp[8];
  if (t < 8) {
    float tn = (float)(t + 1) * 0.375f;         // t_n = (n+1)/8*3, exact fp32
    wtmp[t] = expf(-0.5f * tn * tn);
  }
  if (t < 24) {
    float th = (6.283185307179586f * (float)t) / 24.0f;  // match jax fp32 order
    float c = cosf(th), s = sinf(th);
    const float sc = (float)(512.0 / 511.0);
    tbl[t] = c; tbl[24 + t] = s; tbl[48 + t] = c * sc; tbl[72 + t] = s * sc;
  }
  __syncthreads();
  if (t == 0) {
    const float L2E = 1.44269504088896340736f;
    float sum = 0.f;
    for (int n = 0; n < 8; ++n) sum += wtmp[n];
    for (int n = 0; n < 8; ++n) tbl[96 + n] = (wtmp[n] / sum) * L2E;
    float rt = expf(lrt[0]);
    rt = fminf(fmaxf(rt, 0.001f), 2.0f);
    float sg = 1.0f / (1.0f + expf(-rlg[0]));
    float rho = sg * 0.95f + 0.05f;
    tbl[104] = (1.0f / rt) * L2E;
    tbl[105] = 1.0f / (rho + 1e-8f);
    tbl[106] = fmaxf(gain[0], 0.001f);

    // fast-conv verification: expected line-mask pattern (n=4, tol=0.5) +
    // all-equal weights per bank. Dense 49-tap fallback if it fails.
    const int K0[7] = {14,15,23,24,25,33,34};
    const int K1[7] = {2,9,17,24,31,39,46};
    const int K2[7] = {4,11,17,24,31,37,44};
    const int K3[7] = {19,20,23,24,25,28,29};
    const int* KK[4] = {K0,K1,K2,K3};
    int ok = 1;
    for (int o = 0; o < 4; ++o) {
      float w0v = Wb[o * 49 + KK[o][0]];
      if (w0v == 0.f) ok = 0;
      unsigned long long mask = 0;
      for (int t2 = 0; t2 < 7; ++t2) mask |= 1ull << KK[o][t2];
      for (int k = 0; k < 49; ++k) {
        float w = Wb[o * 49 + k];
        int nz = (w != 0.f);
        int want = (int)((mask >> k) & 1ull);
        if (nz != want) ok = 0;
        if (nz && w != w0v) ok = 0;
      }
      tbl[180 + o] = w0v;
    }
    ((int*)tbl)[172] = ok;
  }
}

// Final configuration (best-of across R1-R9): single kernel, all-LDS gather.
// Rationale from the session's counters: the 403M bilinear gathers x 16B/lane
// put the LDS pipe at ~84-90% busy here (123us pipe floor at 12cyc/ds_read_b128);
// every split of that traffic to VMEM (R3/R4/R8) or reload-masking (R7) or
// deeper ILP/occupancy (R5/R6/R9) moved main-kernel time < +-7% and lost its
// gain to a ~10us prepass. This is the plateau configuration.
__global__ __launch_bounds__(256) void gp_main(const float* __restrict__ x,
                                               const float* __restrict__ Wb,
                                               const float* __restrict__ cen,
                                               const float* __restrict__ tbl,
                                               float* __restrict__ out) {
  __shared__ float  Fm[NST];
  __shared__ float  Sm[NST];
  __shared__ float4 Qd[NST];   // pre-differenced quad: bilinear = 1 mul + 3 fma

  const int tx = threadIdx.x;           // 0..63 (one wave per pixel row)
  const int ty = threadIdx.y;           // 0..3
  const int tid = ty * 64 + tx;
  const int bx0 = blockIdx.x * 64 - HALO;
  const int by0 = blockIdx.y * 4 - HALO;
  const int b = blockIdx.z;
  const float* __restrict__ x0p = x + (size_t)b * 2 * 512 * 512;
  const float* __restrict__ x1p = x0p + 512 * 512;

  // Stage Fm = |x|, Sm = x0+x1 with zero halo (zeros-padding for conv AND
  // zeroed bilinear OOB weights fall out automatically).
  #pragma unroll
  for (int it = 0; it < 4; ++it) {
    int idx = tid + it * 256;
    if (idx < NST) {
      int r = idx / TWX, c = idx - r * TWX;
      int gy = by0 + r, gx = bx0 + c;
      float a = 0.f, bv = 0.f;
      if ((unsigned)gx < 512u && (unsigned)gy < 512u) {
        size_t o = (size_t)gy * 512 + gx;
        a = x0p[o];
        bv = x1p[o];
      }
      Fm[idx] = sqrtf(a * a + bv * bv);
      Sm[idx] = a + bv;
    }
  }
  __syncthreads();
  // Pre-differenced quads: s = v.x + fx*v.y + fy*v.z + fx*fy*v.w
  #pragma unroll
  for (int it = 0; it < 4; ++it) {
    int idx = tid + it * 256;
    if (idx < NST) {
      int r = idx / TWX, c = idx - r * TWX;
      int r1 = (r < TWY - 1) ? r + 1 : r;
      int c1 = (c < TWX - 1) ? c + 1 : c;
      float v00 = Fm[r * TWX + c],  v01 = Fm[r * TWX + c1];
      float v10 = Fm[r1 * TWX + c], v11 = Fm[r1 * TWX + c1];
      Qd[idx] = make_float4(v00, v01 - v00, v10 - v00, (v11 - v10) - (v01 - v00));
    }
  }
  __syncthreads();

  const int gi = bx0 + HALO + tx;
  const int gj = by0 + HALO + ty;
  const float SC = (float)(512.0 / 511.0);
  // Local (tile-frame) sample coords are always > 0 -> (int) trunc == floor.
  const float axl = fmaf((float)gi, SC, -0.5f) - (float)bx0;
  const float ayl = fmaf((float)gj, SC, -0.5f) - (float)by0;

  float wn[8];
  #pragma unroll
  for (int n = 0; n < 8; ++n) wn[n] = tbl[96 + n];   // pre-scaled by log2(e)

  // Orientation energy: 24 angles x 8 radii bilinear samples of Fm.
  // atan2 is scale-invariant -> no softmax normalization needed; E*log2e
  // feeds v_exp_f32 directly.
  float SY = 0.f, CX = 0.f;
  for (int q = 0; q < 24; ++q) {
    const float csx = tbl[48 + q];   // uniform s_load
    const float ssy = tbl[72 + q];
    float e2 = 0.f;
    #pragma unroll
    for (int n = 0; n < 8; ++n) {
      const float tn = 0.375f * (float)(n + 1);
      float px = fmaf(-csx, tn, axl);
      float py = fmaf(-ssy, tn, ayl);
      int ix = (int)px;              // trunc == floor (px > 0)
      int iy = (int)py;
      float fx = FRACTF(px);
      float fy = FRACTF(py);
      float4 v = Qd[iy * TWX + ix];
      float fxy = fx * fy;
      float s = fmaf(fx, v.y, v.x);
      s = fmaf(fy, v.z, s);
      s = fmaf(fxy, v.w, s);
      e2 = fmaf(wn[n], s, e2);
    }
    float e = EXP2F(e2);
    SY = fmaf(e, tbl[24 + q], SY);
    CX = fmaf(e, tbl[q], CX);
  }

  // Conv: verified line-mask fast path (equal weights, shared center triples),
  // dense 49-tap fallback otherwise. Center (ty+4, tx+4), stride 72.
  const int* ti = (const int*)tbl;
  const int ccen = (ty + 4) * TWX + tx + 4;
  float a0, a1, a2, a3;
  if (ti[172]) {
    float sCt = Sm[ccen];
    float H3 = (Sm[ccen - 1] + sCt) + Sm[ccen + 1];
    float V3 = (Sm[ccen - TWX] + sCt) + Sm[ccen + TWX];
    a0 = tbl[180] * (H3 + ((Sm[ccen - 75] + Sm[ccen - 74]) + (Sm[ccen + 74] + Sm[ccen + 75])));
    a1 = tbl[181] * (V3 + ((Sm[ccen - 217] + Sm[ccen - 145]) + (Sm[ccen + 145] + Sm[ccen + 217])));
    a2 = tbl[182] * (V3 + ((Sm[ccen - 215] + Sm[ccen - 143]) + (Sm[ccen + 143] + Sm[ccen + 215])));
    a3 = tbl[183] * (H3 + ((Sm[ccen - 70] + Sm[ccen - 69]) + (Sm[ccen + 69] + Sm[ccen + 70])));
  } else {
    a0 = a1 = a2 = a3 = 0.f;
    for (int kj = 0; kj < 7; ++kj)
      for (int ki = 0; ki < 7; ++ki) {
        float s = Sm[(ty + 1 + kj) * TWX + (tx + 1 + ki)];
        int k = kj * 7 + ki;
        a0 = fmaf(s, Wb[k], a0); a1 = fmaf(s, Wb[49 + k], a1);
        a2 = fmaf(s, Wb[98 + k], a2); a3 = fmaf(s, Wb[147 + k], a3);
      }
  }

  // theta = atan2 mod pi. Conditional subtracts are Sterbenz-exact on these
  // ranges (bit-identical to fmodf here).
  const float TP  = 6.283185307179586f;
  const float PIF = 3.14159265358979323846f;
  const float HP  = 1.57079632679489661923f;
  float hat = atan2f(SY, CX);
  float r1 = hat + TP;                          // (pi, 3pi]
  r1 = (r1 >= TP) ? (r1 - TP) : r1;             // == fmodf(hat+TP, TP)
  float theta = (r1 >= PIF) ? (r1 - PIF) : r1;  // == fmodf(r1, PIF)

  const float irt2  = tbl[104];
  const float gamma = tbl[105];
  const float gainc = tbl[106];

  float dist[4];
  #pragma unroll
  for (int o = 0; o < 4; ++o) {
    float d = theta - cen[o] + HP;              // in (-1.2, 4.33)
    d -= (d >= PIF) ? PIF : 0.f;                // == fmodf(d, PIF) here
    d += (d < 0.f) ? PIF : 0.f;
    dist[o] = fabsf(d - HP);
  }
  float mn = fminf(fminf(dist[0], dist[1]), fminf(dist[2], dist[3]));
  float m2 = mn * irt2;
  float eo[4], Z = 0.f;
  #pragma unroll
  for (int o = 0; o < 4; ++o) { eo[o] = EXP2F(fmaf(-irt2, dist[o], m2)); Z += eo[o]; }
  float invZ = 1.0f / Z;
  float sh[4], Zs = 0.f;
  #pragma unroll
  for (int o = 0; o < 4; ++o) {
    sh[o] = EXP2F(gamma * LOG2F(fmaf(eo[o], invZ, 1e-12f)));
    Zs += sh[o];
  }
  float wsi = 1.0f / (Zs + 1e-8f);
  float ov = (a0 * sh[0] + a1 * sh[1] + a2 * sh[2] + a3 * sh[3]) * wsi;

  out[((size_t)b * 512 + gj) * 512 + gi] = gainc * ov;
}

extern "C" void kernel_launch(void* const* d_in, const int* in_sizes, int n_in,
                              void* d_out, int out_size, void* d_ws, size_t ws_size,
                              hipStream_t stream) {
  const float* x    = (const float*)d_in[0];
  const float* gain = (const float*)d_in[1];
  const float* lrt  = (const float*)d_in[2];
  const float* rlg  = (const float*)d_in[3];
  const float* Wb   = (const float*)d_in[4];
  const float* cen  = (const float*)d_in[5];
  float* tbl = (float*)d_ws;

  gp_setup<<<1, 64, 0, stream>>>(gain, lrt, rlg, Wb, tbl);

  dim3 grid(8, 128, 8);
  dim3 blk(64, 4);
  gp_main<<<grid, blk, 0, stream>>>(x, Wb, cen, tbl, (float*)d_out);
}